// Round 19
// baseline (418.127 us; speedup 1.0000x reference)
//
#include <hip/hip_runtime.h>
#include <hip/hip_bf16.h>

namespace {

constexpr int CB   = 32;            // batch
constexpr int CS   = 64;            // seq len
constexpr int CDIN = 256;           // encoder hidden
constexpr int CH   = 256;           // LSTM hidden / GAT feature
constexpr int CE   = 128;           // embedding dim
constexpr int CV   = 128;           // vocab
constexpr int CGH  = 64;            // per-head GAT dim
constexpr int CNH  = 4;             // heads
constexpr int CN   = 128;           // graph nodes
constexpr int CDX  = CDIN + CE;     // 384 LSTM input
constexpr int CG   = 4 * CH;        // 1024 gates
constexpr int CM   = CB * CS;       // 2048 tokens
constexpr int QLDS = 36;            // weight pairs per gate in LDS (144 KB)
constexpr int QSTR = 128 - QLDS;    // 92 streamed pairs (23 f16x8 chunks)

typedef _Float16 f16x2 __attribute__((ext_vector_type(2)));   // 4 B = 1 float slot
typedef _Float16 f16x8 __attribute__((ext_vector_type(8)));
typedef float    f32x4 __attribute__((ext_vector_type(4)));

__device__ __forceinline__ float leakyf(float x) { return x >= 0.f ? x : 0.2f * x; }
__device__ __forceinline__ float fexpf(float x)  { return __expf(x); }
__device__ __forceinline__ float eluf(float x)   { return x > 0.f ? x : __expf(x) - 1.f; }
__device__ __forceinline__ float sigmf(float x)  { return 1.f / (1.f + __expf(-x)); }
__device__ __forceinline__ float tanhfast(float x) { return 1.f - 2.f / (__expf(2.f * x) + 1.f); }
__device__ __forceinline__ float wredf(float v) {
  #pragma unroll
  for (int off = 32; off; off >>= 1) v += __shfl_xor(v, off);
  return v;
}
__device__ __forceinline__ bool bit128(unsigned long long lo, unsigned long long hi, int j) {
  return ((j < 64 ? (lo >> j) : (hi >> (j - 64))) & 1ull) != 0;
}
#define F2(a, b, c) __builtin_amdgcn_fdot2((a), (b), (c), false)
#define PAIR0(v) __builtin_shufflevector((v), (v), 0, 1)
#define PAIR1(v) __builtin_shufflevector((v), (v), 2, 3)
#define PAIR2(v) __builtin_shufflevector((v), (v), 4, 5)
#define PAIR3(v) __builtin_shufflevector((v), (v), 6, 7)

// Merged xg + prep kernel, 545 blocks x 256 threads. [r18 verbatim]
__global__ __launch_bounds__(256) void k_prep_xg(
    const float* __restrict__ hidden, const int* __restrict__ forced,
    const float* __restrict__ emb, const float* __restrict__ initt,
    const float* __restrict__ Wih, const float* __restrict__ bih,
    const float* __restrict__ bhh, float* __restrict__ xg,
    const float* __restrict__ Whh, const float* __restrict__ intent,
    const float* __restrict__ Wh, const float* __restrict__ ah,
    const float* __restrict__ Wo, const float* __restrict__ ao,
    const int* __restrict__ adj,
    f16x2* __restrict__ Wd, f16x2* __restrict__ Ws,
    float* __restrict__ hint, float* __restrict__ f1int, float* __restrict__ f2int,
    float* __restrict__ woao1, float* __restrict__ woao2,
    unsigned long long* __restrict__ masks) {
  __shared__ __align__(16) char pxs[12288];
  int tid = threadIdx.x;
  int bid = blockIdx.x;

  if (bid < 256) {                  // ---- xg path
    f32x4 (*xs)[CDX / 4] = (f32x4(*)[CDX / 4])pxs;
    int m0 = bid * 8;
    for (int idx = tid; idx < 8 * (CDX / 4); idx += 256) {
      int r = idx / (CDX / 4), q = idx - r * (CDX / 4);
      int m = m0 + r;
      f32x4 v;
      if (q < CDIN / 4) {
        v = ((const f32x4*)hidden)[m * (CDIN / 4) + q];
      } else {
        int e4 = q - CDIN / 4;
        if ((m & 63) == 0) v = ((const f32x4*)initt)[e4];
        else               v = ((const f32x4*)emb)[forced[m - 1] * (CE / 4) + e4];
      }
      xs[r][q] = v;
    }
    __syncthreads();
    int g0 = tid * 4;
    float acc[8][4];
    #pragma unroll
    for (int r = 0; r < 8; ++r)
      #pragma unroll
      for (int jj = 0; jj < 4; ++jj) acc[r][jj] = 0.f;
    const f32x4* w0 = (const f32x4*)(Wih + (g0 + 0) * CDX);
    const f32x4* w1 = (const f32x4*)(Wih + (g0 + 1) * CDX);
    const f32x4* w2 = (const f32x4*)(Wih + (g0 + 2) * CDX);
    const f32x4* w3 = (const f32x4*)(Wih + (g0 + 3) * CDX);
    #pragma unroll 2
    for (int q = 0; q < CDX / 4; ++q) {
      f32x4 wa = w0[q], wb = w1[q], wc = w2[q], wd4 = w3[q];
      #pragma unroll
      for (int r = 0; r < 8; ++r) {
        f32x4 xv = xs[r][q];
        acc[r][0] += wa.x * xv.x + wa.y * xv.y + wa.z * xv.z + wa.w * xv.w;
        acc[r][1] += wb.x * xv.x + wb.y * xv.y + wb.z * xv.z + wb.w * xv.w;
        acc[r][2] += wc.x * xv.x + wc.y * xv.y + wc.z * xv.z + wc.w * xv.w;
        acc[r][3] += wd4.x * xv.x + wd4.y * xv.y + wd4.z * xv.z + wd4.w * xv.w;
      }
    }
    f32x4 bias = { bih[g0] + bhh[g0], bih[g0 + 1] + bhh[g0 + 1],
                   bih[g0 + 2] + bhh[g0 + 2], bih[g0 + 3] + bhh[g0 + 3] };
    #pragma unroll
    for (int r = 0; r < 8; ++r) {
      f32x4 st = { acc[r][0] + bias.x, acc[r][1] + bias.y,
                   acc[r][2] + bias.z, acc[r][3] + bias.w };
      ((f32x4*)xg)[((m0 + r) * CG + g0) / 4] = st;
    }
    return;
  }

  int pb = bid - 256;
  if (pb < 256) {                   // ---- W_hh pack
    int g = pb * 4 + (tid >> 6);
    int c = tid & 63;
    const float2* row = (const float2*)(Whh + g * CH);
    #pragma unroll
    for (int hh = 0; hh < 2; ++hh) {
      int q = c + 64 * hh;
      float2 wp = row[q];
      f16x2 w = { (_Float16)wp.x, (_Float16)wp.y };
      if (q < QLDS) {
        Wd[q * CG + g] = w;
      } else {
        int qs = q - QLDS, jc = qs >> 2, sub = qs & 3;
        Ws[(jc * CG + g) * 4 + sub] = w;
      }
    }
  } else if (pb < 272) {            // ---- hint
    float (*ls)[CH] = (float(*)[CH])pxs;
    int i0 = (pb - 256) * 8;
    int k = tid >> 6, c = tid & 63;
    for (int idx = tid; idx < 8 * CH; idx += 256) {
      int r = idx >> 8, d = idx & 255;
      int i = i0 + r;
      ls[r][d] = (i < 127) ? intent[i * CH + d] : 0.f;
    }
    __syncthreads();
    float acc[8];
    #pragma unroll
    for (int r = 0; r < 8; ++r) acc[r] = 0.f;
    #pragma unroll 4
    for (int d = 0; d < CH; ++d) {
      float w = Wh[(k * CH + d) * CGH + c];
      #pragma unroll
      for (int r = 0; r < 8; ++r) acc[r] += w * ls[r][d];
    }
    float a1 = ah[k * 128 + c], a2 = ah[k * 128 + 64 + c];
    #pragma unroll
    for (int r = 0; r < 8; ++r) {
      int i = i0 + r;
      float r1 = wredf(acc[r] * a1);
      float r2 = wredf(acc[r] * a2);
      if (i < 127) {
        hint[(k * 128 + i) * CGH + c] = acc[r];
        if (c == 0) { f1int[k * 128 + i] = r1; f2int[k * 128 + i] = r2; }
      }
    }
  } else if (pb < 288) {            // ---- woao
    int wave = tid >> 6, c = tid & 63;
    #pragma unroll
    for (int it = 0; it < 8; ++it) {
      int o = (pb - 272) * 32 + it * 4 + wave;
      int orow = (o < 256) ? o : o - 256;
      int abase = (o < 256) ? 0 : CH;
      const float* row = Wo + orow * CH;
      float acc = row[c] * ao[abase + c] + row[64 + c] * ao[abase + 64 + c]
                + row[128 + c] * ao[abase + 128 + c] + row[192 + c] * ao[abase + 192 + c];
      acc = wredf(acc);
      if (c == 0) {
        if (o < 256) woao1[o] = acc;
        else         woao2[o - 256] = acc;
      }
    }
  } else {                          // ---- adjacency masks
    int wave = tid >> 6, c = tid & 63;
    for (int b = 0; b < CB; ++b) {
      const int base = b * CN * CN;
      int v;
      if (wave == 0)      v = adj[base + c * CN];
      else if (wave == 1) v = adj[base + (64 + c) * CN];
      else if (wave == 2) v = adj[base + c];
      else                v = adj[base + 64 + c];
      unsigned long long m = __ballot(v != 0);
      if (c == 0) masks[b * 4 + wave] = m;
    }
  }
}

// Merged LSTM + U kernel, 288 blocks x 1024 threads. [r18 structure]
// ONLY change vs r18: the LSTM dot uses 4 independent accumulators to break
// the 128-deep fdot2 dependency chain (latency-bound at 2 waves/SIMD).
__global__ __launch_bounds__(1024) void k_lstm_u(
    const float* __restrict__ xg, const f16x2* __restrict__ Wd,
    const f16x2* __restrict__ Ws, float* __restrict__ lo,
    const float* __restrict__ hint, const float* __restrict__ f1int,
    const float* __restrict__ f2int, const int* __restrict__ adj,
    float* __restrict__ U, float* __restrict__ wS) {
  __shared__ __align__(16) char smemraw[QLDS * CG * 4 + CG * 4 + (CH / 8) * 16];
  int tid = threadIdx.x;

  if (blockIdx.x < CB) {
    // ---------------- LSTM path ----------------
    f16x2* wd  = (f16x2*)smemraw;                         // 147456 B
    float* gbuf = (float*)(smemraw + QLDS * CG * 4);      // 4 KB
    f16x8* hs8  = (f16x8*)(smemraw + QLDS * CG * 4 + CG * 4);  // 512 B
    _Float16* hsh = (_Float16*)hs8;
    int b = blockIdx.x;
    int g = tid;

    for (int i = g; i < QLDS * CG; i += CG) wd[i] = Wd[i];
    if (g < CH) hsh[g] = (_Float16)0.f;
    float c = 0.f;
    __syncthreads();

    const float* xgb = xg + b * CS * CG;
    float nx = xgb[g];
    unsigned long long wsa = (unsigned long long)Ws;

    for (int t = 0; t < CS; ++t) {
      float acc0 = nx, acc1 = 0.f, acc2 = 0.f, acc3 = 0.f;
      if (t + 1 < CS) nx = xgb[(t + 1) * CG + g];
      asm volatile("" : "+v"(wsa));
      const f16x8* wsp = (const f16x8*)wsa;

      // LDS-resident pairs 0..35 (chunks 0..8), round-robin over 4 accs
      #pragma unroll
      for (int hc = 0; hc < QLDS / 4; ++hc) {
        f16x8 hv = hs8[hc];
        acc0 = F2(wd[(4 * hc + 0) * CG + g], PAIR0(hv), acc0);
        acc1 = F2(wd[(4 * hc + 1) * CG + g], PAIR1(hv), acc1);
        acc2 = F2(wd[(4 * hc + 2) * CG + g], PAIR2(hv), acc2);
        acc3 = F2(wd[(4 * hc + 3) * CG + g], PAIR3(hv), acc3);
      }
      // streamed pairs 36..127 (chunks 9..31), round-robin over 4 accs
      #pragma unroll
      for (int jc = 0; jc < QSTR / 4; ++jc) {
        f16x8 wv = wsp[jc * CG + g];
        f16x8 hv = hs8[QLDS / 4 + jc];
        acc0 = F2(PAIR0(wv), PAIR0(hv), acc0);
        acc1 = F2(PAIR1(wv), PAIR1(hv), acc1);
        acc2 = F2(PAIR2(wv), PAIR2(hv), acc2);
        acc3 = F2(PAIR3(wv), PAIR3(hv), acc3);
      }
      gbuf[g] = (acc0 + acc1) + (acc2 + acc3);
      __syncthreads();
      if (g < CH) {
        float gi = gbuf[g], gf = gbuf[CH + g], gg = gbuf[2 * CH + g], go = gbuf[3 * CH + g];
        c = sigmf(gf) * c + sigmf(gi) * tanhfast(gg);
        float h = sigmf(go) * tanhfast(c);
        lo[(b * CS + t) * CH + g] = h;
        hsh[g] = (_Float16)h;
      }
      __syncthreads();
    }
    return;
  }

  // ---------------- U path (r18 verbatim) ----------------
  float* hs = (float*)smemraw;
  float (*wbuf)[128] = (float(*)[128])(smemraw + 32512);
  float* f2s = (float*)(smemraw + 32512 + 8192);
  int ub = blockIdx.x - CB;
  int b = ub >> 3;
  int k = (ub >> 1) & 3;
  int half = ub & 1;
  int grp = tid >> 6, c = tid & 63;

  for (int idx = tid; idx < 127 * CGH; idx += 1024)
    hs[idx] = hint[k * 128 * CGH + idx];
  if (tid < 127) f2s[tid] = f2int[k * 128 + tid];
  __syncthreads();
  const int adjb = b * CN * CN;
  int ibeg = 1 + 64 * half;
  int iend = half ? 128 : 65;
  for (int i = ibeg + grp; i < iend; i += 16) {
    float f1 = f1int[k * 128 + (i - 1)];
    int j1 = 1 + c, j2 = 65 + c;
    float w1 = 0.f, w2 = 0.f;
    if (adj[adjb + i * CN + j1]) w1 = fexpf(leakyf(f1 + f2s[j1 - 1]));
    if (j2 < 128 && adj[adjb + i * CN + j2]) w2 = fexpf(leakyf(f1 + f2s[j2 - 1]));
    wbuf[grp][c] = w1;
    wbuf[grp][64 + c] = w2;
    float rs = wredf(w1 + w2);
    float acc = 0.f;
    #pragma unroll 4
    for (int jj = 0; jj < 127; ++jj)
      acc += wbuf[grp][jj] * hs[jj * CGH + c];
    if (c == 0) wS[(b * 4 + k) * 128 + i] = rs;
    U[((b * 4 + k) * 128 + i) * CGH + c] = acc;
  }
}

// htok / f1tok / f2tok [r12 verbatim]
__global__ void k_htok(const float* __restrict__ lo, const float* __restrict__ Wh,
                       const float* __restrict__ ah, float* __restrict__ htok,
                       float* __restrict__ f1tok, float* __restrict__ f2tok) {
  __shared__ float ls[8][CH];
  int m0 = blockIdx.x * 8;
  int tid = threadIdx.x;
  int k = tid >> 6, c = tid & 63;
  for (int idx = tid; idx < 8 * CH; idx += 256) {
    int r = idx >> 8, d = idx & 255;
    ls[r][d] = lo[(m0 + r) * CH + d];
  }
  __syncthreads();
  float acc[8];
  #pragma unroll
  for (int r = 0; r < 8; ++r) acc[r] = 0.f;
  #pragma unroll 4
  for (int d = 0; d < CH; ++d) {
    float w = Wh[(k * CH + d) * CGH + c];
    #pragma unroll
    for (int r = 0; r < 8; ++r) acc[r] += w * ls[r][d];
  }
  float a1 = ah[k * 128 + c], a2 = ah[k * 128 + 64 + c];
  #pragma unroll
  for (int r = 0; r < 8; ++r) {
    htok[(m0 + r) * CH + tid] = acc[r];
    float r1 = wredf(acc[r] * a1);
    float r2 = wredf(acc[r] * a2);
    if (c == 0) { f1tok[(m0 + r) * CNH + k] = r1; f2tok[(m0 + r) * CNH + k] = r2; }
  }
}

// Per-token fused GAT layer-2 + logits; bitmask adjacency; fast exp. [r15 verbatim]
__global__ __launch_bounds__(256) void k_perm3(
    const float* __restrict__ lo, const float* __restrict__ htok,
    const float* __restrict__ f1tok, const float* __restrict__ f2tok,
    const float* __restrict__ hint, const float* __restrict__ f1int,
    const float* __restrict__ f2int, const float* __restrict__ U,
    const float* __restrict__ wS, const float* __restrict__ woao1,
    const float* __restrict__ woao2, const unsigned long long* __restrict__ masks,
    const float* __restrict__ Wo, const float* __restrict__ Wl,
    const float* __restrict__ bl, const int* __restrict__ seq_lens,
    float* __restrict__ out) {
  int m = blockIdx.x;
  int b = m >> 6, s = m & 63;
  int tid = threadIdx.x;
  int k = tid >> 6, c = tid & 63;

  __shared__ float ht[CH];
  __shared__ float s1[CNH][CN];
  __shared__ float s2[CNH][CN];
  __shared__ float w0[CNH][CN];
  __shared__ float x10[CH];
  __shared__ float f22[CN];
  __shared__ float w2s[CN];
  __shared__ float ybuf[CH];
  __shared__ float gbuf[CH];
  __shared__ float part[2][CV];
  __shared__ int   list[CN];
  __shared__ int   cnt;
  __shared__ float f12s, f220s, den2s;

  const unsigned long long c0lo = masks[b * 4 + 0], c0hi = masks[b * 4 + 1];
  const unsigned long long r0lo = masks[b * 4 + 2], r0hi = masks[b * 4 + 3];

  ht[tid] = htok[m * CH + tid];
  float f1t = f1tok[m * CNH + k];
  float f2t = f2tok[m * CNH + k];

  if (k == 0) {
    int j1 = 1 + c;
    int j2 = 65 + c;
    bool fl1 = bit128(r0lo, r0hi, j1);
    bool fl2 = (j2 < CN) && bit128(r0lo, r0hi, j2);
    unsigned long long b1 = __ballot(fl1);
    unsigned long long b2 = __ballot(fl2);
    unsigned long long below = (1ull << c) - 1ull;
    int n1 = __popcll(b1);
    if (fl1) list[__popcll(b1 & below)] = j1;
    if (fl2) list[n1 + __popcll(b2 & below)] = j2;
    if (c == 0) cnt = n1 + __popcll(b2);
  }

  for (int idx = tid; idx < CNH * CN; idx += 256) {
    int k2 = idx >> 7, i = idx & 127;
    if (i == 0) continue;
    float t0 = 0.f;
    if (bit128(c0lo, c0hi, i)) t0 = fexpf(leakyf(f1int[k2 * 128 + i - 1] + f2tok[m * CNH + k2]));
    float rd = 1.f / (wS[(b * 4 + k2) * 128 + i] + t0);
    s1[k2][i] = rd;
    s2[k2][i] = t0 * rd;
  }

  float den0;
  {
    int j1 = c, j2 = c + 64;
    float e1 = leakyf(f1t + (j1 == 0 ? f2t : f2int[k * 128 + j1 - 1]));
    float wj1 = bit128(r0lo, r0hi, j1) ? fexpf(e1) : 0.f;
    float e2 = leakyf(f1t + f2int[k * 128 + j2 - 1]);
    float wj2 = bit128(r0lo, r0hi, j2) ? fexpf(e2) : 0.f;
    w0[k][j1] = wj1;
    w0[k][j2] = wj2;
    den0 = wredf(wj1 + wj2);
  }
  __syncthreads();
  const int na = cnt;

  {
    float acc = w0[k][0] * ht[tid];
    #pragma unroll 4
    for (int l = 0; l < na; ++l) {
      int j = list[l];
      acc += w0[k][j] * hint[(k * 128 + j - 1) * CGH + c];
    }
    x10[tid] = eluf(acc / den0);
  }
  __syncthreads();

  if (k == 0) {
    float p = x10[c] * woao1[c] + x10[c + 64] * woao1[c + 64]
            + x10[c + 128] * woao1[c + 128] + x10[c + 192] * woao1[c + 192];
    p = wredf(p);
    if (c == 0) f12s = p;
  }
  if (k == 1) {
    float p = x10[c] * woao2[c] + x10[c + 64] * woao2[c + 64]
            + x10[c + 128] * woao2[c + 128] + x10[c + 192] * woao2[c + 192];
    p = wredf(p);
    if (c == 0) f220s = p;
  }
  for (int l = k; l < na; l += 4) {
    int j = list[l];
    float p = 0.f;
    #pragma unroll
    for (int kk = 0; kk < 4; ++kk) {
      float u = U[((b * 4 + kk) * 128 + j) * CGH + c];
      float val = eluf(u * s1[kk][j] + s2[kk][j] * ht[kk * 64 + c]);
      p += val * woao2[kk * 64 + c];
    }
    p = wredf(p);
    if (c == 0) f22[l] = p;
  }
  __syncthreads();

  float w20 = fexpf(leakyf(f12s + f220s));
  if (tid < na) w2s[tid] = fexpf(leakyf(f12s + f22[tid]));
  __syncthreads();
  if (k == 0) {
    float v = (c < na ? w2s[c] : 0.f) + (c + 64 < na ? w2s[c + 64] : 0.f);
    v = wredf(v);
    if (c == 0) den2s = v + w20;
  }

  {
    float yacc = w20 * x10[tid];
    #pragma unroll 4
    for (int l = 0; l < na; ++l) {
      int j = list[l];
      float u = U[((b * 4 + k) * 128 + j) * CGH + c];
      float val = eluf(u * s1[k][j] + s2[k][j] * ht[tid]);
      yacc += w2s[l] * val;
    }
    ybuf[tid] = yacc;
  }
  __syncthreads();

  float hacc = 0.f;
  #pragma unroll 8
  for (int kk = 0; kk < CH; ++kk) hacc += ybuf[kk] * Wo[kk * CH + tid];
  float g = eluf(hacc / den2s) + lo[m * CH + tid];
  gbuf[tid] = g;
  __syncthreads();

  {
    int col = tid & 127, hh = tid >> 7;
    float acc = 0.f;
    #pragma unroll 8
    for (int cc = hh * 128; cc < hh * 128 + 128; ++cc) acc += gbuf[cc] * Wl[cc * CV + col];
    part[hh][col] = acc;
  }
  __syncthreads();
  if (tid < CV) {
    float r = part[0][tid] + part[1][tid] + bl[tid];
    out[m * CV + tid] = (s < seq_lens[b]) ? r : 0.f;
  }
}

}  // namespace

extern "C" void kernel_launch(void* const* d_in, const int* in_sizes, int n_in,
                              void* d_out, int out_size, void* d_ws, size_t ws_size,
                              hipStream_t stream) {
  const float* hidden   = (const float*)d_in[0];
  const int*   seq_lens = (const int*)d_in[1];
  const int*   forced   = (const int*)d_in[2];
  const int*   adj      = (const int*)d_in[3];
  const float* intent   = (const float*)d_in[4];
  const float* emb      = (const float*)d_in[5];
  const float* initt    = (const float*)d_in[6];
  const float* W_ih     = (const float*)d_in[7];
  const float* W_hh     = (const float*)d_in[8];
  const float* b_ih     = (const float*)d_in[9];
  const float* b_hh     = (const float*)d_in[10];
  const float* Wh       = (const float*)d_in[11];
  const float* ah       = (const float*)d_in[12];
  const float* Wo       = (const float*)d_in[13];
  const float* ao       = (const float*)d_in[14];
  const float* Wl       = (const float*)d_in[15];
  const float* bl       = (const float*)d_in[16];
  float* out = (float*)d_out;

  // Layout (1 f16x2 = 1 float slot — verified r12).
  float* ws    = (float*)d_ws;
  float* WdF   = ws;                        // QLDS*CG = 36864 slots
  float* WsF   = WdF + QLDS * CG;           // QSTR*CG = 94208 slots
  float* xg    = WsF + QSTR * CG;           // 2097152
  float* lo    = xg + CM * CG;              // 524288
  float* htok  = lo + CM * CH;              // 524288
  float* f1tok = htok + CM * CH;            // 8192
  float* f2tok = f1tok + CM * CNH;          // 8192
  float* hint  = f2tok + CM * CNH;          // 32768
  float* f1int = hint + CNH * 128 * CGH;    // 512
  float* f2int = f1int + CNH * 128;         // 512
  float* U     = f2int + CNH * 128;         // 1048576
  float* wS    = U + CB * CNH * 128 * CGH;  // 16384
  float* woao1 = wS + CB * CNH * 128;       // 256
  float* woao2 = woao1 + CH;                // 256
  unsigned long long* masks = (unsigned long long*)(woao2 + CH);  // 32*4 u64
  f16x2* Wd    = (f16x2*)WdF;
  f16x2* Wsp   = (f16x2*)WsF;

  k_prep_xg<<<545, 256, 0, stream>>>(hidden, forced, emb, initt, W_ih, b_ih, b_hh, xg,
                                     W_hh, intent, Wh, ah, Wo, ao, adj,
                                     Wd, Wsp, hint, f1int, f2int, woao1, woao2, masks);
  k_lstm_u<<<CB + CB * CNH * 2, 1024, 0, stream>>>(xg, Wd, Wsp, lo,
                                                   hint, f1int, f2int, adj, U, wS);
  k_htok<<<CM / 8, 256, 0, stream>>>(lo, Wh, ah, htok, f1tok, f2tok);
  k_perm3<<<CM, 256, 0, stream>>>(lo, htok, f1tok, f2tok, hint, f1int, f2int,
                                  U, wS, woao1, woao2, masks, Wo, Wl, bl, seq_lens, out);
}

// Round 20
// 375.399 us; speedup vs baseline: 1.1138x; 1.1138x over previous
//
#include <hip/hip_runtime.h>
#include <hip/hip_bf16.h>

namespace {

constexpr int CB   = 32;            // batch
constexpr int CS   = 64;            // seq len
constexpr int CDIN = 256;           // encoder hidden
constexpr int CH   = 256;           // LSTM hidden / GAT feature
constexpr int CE   = 128;           // embedding dim
constexpr int CV   = 128;           // vocab
constexpr int CGH  = 64;            // per-head GAT dim
constexpr int CNH  = 4;             // heads
constexpr int CN   = 128;           // graph nodes
constexpr int CDX  = CDIN + CE;     // 384 LSTM input
constexpr int CG   = 4 * CH;        // 1024 gates
constexpr int CM   = CB * CS;       // 2048 tokens
constexpr int QLDS = 36;            // weight pairs per gate in LDS (144 KB)
constexpr int QSTR = 128 - QLDS;    // 92 streamed pairs (23 f16x8 chunks)
constexpr int NCH  = QSTR / 4;      // 23 streamed chunks

typedef _Float16 f16x2 __attribute__((ext_vector_type(2)));   // 4 B = 1 float slot
typedef _Float16 f16x8 __attribute__((ext_vector_type(8)));
typedef float    f32x4 __attribute__((ext_vector_type(4)));

__device__ __forceinline__ float leakyf(float x) { return x >= 0.f ? x : 0.2f * x; }
__device__ __forceinline__ float fexpf(float x)  { return __expf(x); }
__device__ __forceinline__ float eluf(float x)   { return x > 0.f ? x : __expf(x) - 1.f; }
__device__ __forceinline__ float sigmf(float x)  { return 1.f / (1.f + __expf(-x)); }
__device__ __forceinline__ float tanhfast(float x) { return 1.f - 2.f / (__expf(2.f * x) + 1.f); }
__device__ __forceinline__ float wredf(float v) {
  #pragma unroll
  for (int off = 32; off; off >>= 1) v += __shfl_xor(v, off);
  return v;
}
__device__ __forceinline__ bool bit128(unsigned long long lo, unsigned long long hi, int j) {
  return ((j < 64 ? (lo >> j) : (hi >> (j - 64))) & 1ull) != 0;
}
#define F2(a, b, c) __builtin_amdgcn_fdot2((a), (b), (c), false)
#define PAIR0(v) __builtin_shufflevector((v), (v), 0, 1)
#define PAIR1(v) __builtin_shufflevector((v), (v), 2, 3)
#define PAIR2(v) __builtin_shufflevector((v), (v), 4, 5)
#define PAIR3(v) __builtin_shufflevector((v), (v), 6, 7)

// Merged xg + prep kernel, 545 blocks x 256 threads. [r18 verbatim]
__global__ __launch_bounds__(256) void k_prep_xg(
    const float* __restrict__ hidden, const int* __restrict__ forced,
    const float* __restrict__ emb, const float* __restrict__ initt,
    const float* __restrict__ Wih, const float* __restrict__ bih,
    const float* __restrict__ bhh, float* __restrict__ xg,
    const float* __restrict__ Whh, const float* __restrict__ intent,
    const float* __restrict__ Wh, const float* __restrict__ ah,
    const float* __restrict__ Wo, const float* __restrict__ ao,
    const int* __restrict__ adj,
    f16x2* __restrict__ Wd, f16x2* __restrict__ Ws,
    float* __restrict__ hint, float* __restrict__ f1int, float* __restrict__ f2int,
    float* __restrict__ woao1, float* __restrict__ woao2,
    unsigned long long* __restrict__ masks) {
  __shared__ __align__(16) char pxs[12288];
  int tid = threadIdx.x;
  int bid = blockIdx.x;

  if (bid < 256) {                  // ---- xg path
    f32x4 (*xs)[CDX / 4] = (f32x4(*)[CDX / 4])pxs;
    int m0 = bid * 8;
    for (int idx = tid; idx < 8 * (CDX / 4); idx += 256) {
      int r = idx / (CDX / 4), q = idx - r * (CDX / 4);
      int m = m0 + r;
      f32x4 v;
      if (q < CDIN / 4) {
        v = ((const f32x4*)hidden)[m * (CDIN / 4) + q];
      } else {
        int e4 = q - CDIN / 4;
        if ((m & 63) == 0) v = ((const f32x4*)initt)[e4];
        else               v = ((const f32x4*)emb)[forced[m - 1] * (CE / 4) + e4];
      }
      xs[r][q] = v;
    }
    __syncthreads();
    int g0 = tid * 4;
    float acc[8][4];
    #pragma unroll
    for (int r = 0; r < 8; ++r)
      #pragma unroll
      for (int jj = 0; jj < 4; ++jj) acc[r][jj] = 0.f;
    const f32x4* w0 = (const f32x4*)(Wih + (g0 + 0) * CDX);
    const f32x4* w1 = (const f32x4*)(Wih + (g0 + 1) * CDX);
    const f32x4* w2 = (const f32x4*)(Wih + (g0 + 2) * CDX);
    const f32x4* w3 = (const f32x4*)(Wih + (g0 + 3) * CDX);
    #pragma unroll 2
    for (int q = 0; q < CDX / 4; ++q) {
      f32x4 wa = w0[q], wb = w1[q], wc = w2[q], wd4 = w3[q];
      #pragma unroll
      for (int r = 0; r < 8; ++r) {
        f32x4 xv = xs[r][q];
        acc[r][0] += wa.x * xv.x + wa.y * xv.y + wa.z * xv.z + wa.w * xv.w;
        acc[r][1] += wb.x * xv.x + wb.y * xv.y + wb.z * xv.z + wb.w * xv.w;
        acc[r][2] += wc.x * xv.x + wc.y * xv.y + wc.z * xv.z + wc.w * xv.w;
        acc[r][3] += wd4.x * xv.x + wd4.y * xv.y + wd4.z * xv.z + wd4.w * xv.w;
      }
    }
    f32x4 bias = { bih[g0] + bhh[g0], bih[g0 + 1] + bhh[g0 + 1],
                   bih[g0 + 2] + bhh[g0 + 2], bih[g0 + 3] + bhh[g0 + 3] };
    #pragma unroll
    for (int r = 0; r < 8; ++r) {
      f32x4 st = { acc[r][0] + bias.x, acc[r][1] + bias.y,
                   acc[r][2] + bias.z, acc[r][3] + bias.w };
      ((f32x4*)xg)[((m0 + r) * CG + g0) / 4] = st;
    }
    return;
  }

  int pb = bid - 256;
  if (pb < 256) {                   // ---- W_hh pack
    int g = pb * 4 + (tid >> 6);
    int c = tid & 63;
    const float2* row = (const float2*)(Whh + g * CH);
    #pragma unroll
    for (int hh = 0; hh < 2; ++hh) {
      int q = c + 64 * hh;
      float2 wp = row[q];
      f16x2 w = { (_Float16)wp.x, (_Float16)wp.y };
      if (q < QLDS) {
        Wd[q * CG + g] = w;
      } else {
        int qs = q - QLDS, jc = qs >> 2, sub = qs & 3;
        Ws[(jc * CG + g) * 4 + sub] = w;
      }
    }
  } else if (pb < 272) {            // ---- hint
    float (*ls)[CH] = (float(*)[CH])pxs;
    int i0 = (pb - 256) * 8;
    int k = tid >> 6, c = tid & 63;
    for (int idx = tid; idx < 8 * CH; idx += 256) {
      int r = idx >> 8, d = idx & 255;
      int i = i0 + r;
      ls[r][d] = (i < 127) ? intent[i * CH + d] : 0.f;
    }
    __syncthreads();
    float acc[8];
    #pragma unroll
    for (int r = 0; r < 8; ++r) acc[r] = 0.f;
    #pragma unroll 4
    for (int d = 0; d < CH; ++d) {
      float w = Wh[(k * CH + d) * CGH + c];
      #pragma unroll
      for (int r = 0; r < 8; ++r) acc[r] += w * ls[r][d];
    }
    float a1 = ah[k * 128 + c], a2 = ah[k * 128 + 64 + c];
    #pragma unroll
    for (int r = 0; r < 8; ++r) {
      int i = i0 + r;
      float r1 = wredf(acc[r] * a1);
      float r2 = wredf(acc[r] * a2);
      if (i < 127) {
        hint[(k * 128 + i) * CGH + c] = acc[r];
        if (c == 0) { f1int[k * 128 + i] = r1; f2int[k * 128 + i] = r2; }
      }
    }
  } else if (pb < 288) {            // ---- woao
    int wave = tid >> 6, c = tid & 63;
    #pragma unroll
    for (int it = 0; it < 8; ++it) {
      int o = (pb - 272) * 32 + it * 4 + wave;
      int orow = (o < 256) ? o : o - 256;
      int abase = (o < 256) ? 0 : CH;
      const float* row = Wo + orow * CH;
      float acc = row[c] * ao[abase + c] + row[64 + c] * ao[abase + 64 + c]
                + row[128 + c] * ao[abase + 128 + c] + row[192 + c] * ao[abase + 192 + c];
      acc = wredf(acc);
      if (c == 0) {
        if (o < 256) woao1[o] = acc;
        else         woao2[o - 256] = acc;
      }
    }
  } else {                          // ---- adjacency masks
    int wave = tid >> 6, c = tid & 63;
    for (int b = 0; b < CB; ++b) {
      const int base = b * CN * CN;
      int v;
      if (wave == 0)      v = adj[base + c * CN];
      else if (wave == 1) v = adj[base + (64 + c) * CN];
      else if (wave == 2) v = adj[base + c];
      else                v = adj[base + 64 + c];
      unsigned long long m = __ballot(v != 0);
      if (c == 0) masks[b * 4 + wave] = m;
    }
  }
}

// Merged LSTM + U kernel, 288 blocks x 1024 threads. [r19 structure]
// ONLY change vs r19: all 23 streamed weight chunks are hoisted into a
// register array BEFORE consumption (92 VGPRs of loads in flight; the block
// is 16 waves/CU so up to 128 VGPRs/wave are available). This converts the
// stream from latency-parallelism-bound (VGPR=52 -> ~6 loads in flight) to
// bandwidth-bound.
__global__ __launch_bounds__(1024) void k_lstm_u(
    const float* __restrict__ xg, const f16x2* __restrict__ Wd,
    const f16x2* __restrict__ Ws, float* __restrict__ lo,
    const float* __restrict__ hint, const float* __restrict__ f1int,
    const float* __restrict__ f2int, const int* __restrict__ adj,
    float* __restrict__ U, float* __restrict__ wS) {
  __shared__ __align__(16) char smemraw[QLDS * CG * 4 + CG * 4 + (CH / 8) * 16];
  int tid = threadIdx.x;

  if (blockIdx.x < CB) {
    // ---------------- LSTM path ----------------
    f16x2* wd  = (f16x2*)smemraw;                         // 147456 B
    float* gbuf = (float*)(smemraw + QLDS * CG * 4);      // 4 KB
    f16x8* hs8  = (f16x8*)(smemraw + QLDS * CG * 4 + CG * 4);  // 512 B
    _Float16* hsh = (_Float16*)hs8;
    int b = blockIdx.x;
    int g = tid;

    for (int i = g; i < QLDS * CG; i += CG) wd[i] = Wd[i];
    if (g < CH) hsh[g] = (_Float16)0.f;
    float c = 0.f;
    __syncthreads();

    const float* xgb = xg + b * CS * CG;
    float nx = xgb[g];
    unsigned long long wsa = (unsigned long long)Ws;

    for (int t = 0; t < CS; ++t) {
      float acc0 = nx, acc1 = 0.f, acc2 = 0.f, acc3 = 0.f;
      if (t + 1 < CS) nx = xgb[(t + 1) * CG + g];
      asm volatile("" : "+v"(wsa));
      const f16x8* wsp = (const f16x8*)wsa;

      // Issue ALL 23 streamed loads first (92 VGPRs in flight).
      f16x8 wv[NCH];
      #pragma unroll
      for (int jc = 0; jc < NCH; ++jc) wv[jc] = wsp[jc * CG + g];

      // LDS-resident pairs 0..35 (chunks 0..8) — overlaps the load returns.
      #pragma unroll
      for (int hc = 0; hc < QLDS / 4; ++hc) {
        f16x8 hv = hs8[hc];
        acc0 = F2(wd[(4 * hc + 0) * CG + g], PAIR0(hv), acc0);
        acc1 = F2(wd[(4 * hc + 1) * CG + g], PAIR1(hv), acc1);
        acc2 = F2(wd[(4 * hc + 2) * CG + g], PAIR2(hv), acc2);
        acc3 = F2(wd[(4 * hc + 3) * CG + g], PAIR3(hv), acc3);
      }
      // Consume streamed chunks 9..31 in order (waitcnt descends).
      #pragma unroll
      for (int jc = 0; jc < NCH; ++jc) {
        f16x8 hv = hs8[QLDS / 4 + jc];
        acc0 = F2(PAIR0(wv[jc]), PAIR0(hv), acc0);
        acc1 = F2(PAIR1(wv[jc]), PAIR1(hv), acc1);
        acc2 = F2(PAIR2(wv[jc]), PAIR2(hv), acc2);
        acc3 = F2(PAIR3(wv[jc]), PAIR3(hv), acc3);
      }
      gbuf[g] = (acc0 + acc1) + (acc2 + acc3);
      __syncthreads();
      if (g < CH) {
        float gi = gbuf[g], gf = gbuf[CH + g], gg = gbuf[2 * CH + g], go = gbuf[3 * CH + g];
        c = sigmf(gf) * c + sigmf(gi) * tanhfast(gg);
        float h = sigmf(go) * tanhfast(c);
        lo[(b * CS + t) * CH + g] = h;
        hsh[g] = (_Float16)h;
      }
      __syncthreads();
    }
    return;
  }

  // ---------------- U path (r18 verbatim) ----------------
  float* hs = (float*)smemraw;
  float (*wbuf)[128] = (float(*)[128])(smemraw + 32512);
  float* f2s = (float*)(smemraw + 32512 + 8192);
  int ub = blockIdx.x - CB;
  int b = ub >> 3;
  int k = (ub >> 1) & 3;
  int half = ub & 1;
  int grp = tid >> 6, c = tid & 63;

  for (int idx = tid; idx < 127 * CGH; idx += 1024)
    hs[idx] = hint[k * 128 * CGH + idx];
  if (tid < 127) f2s[tid] = f2int[k * 128 + tid];
  __syncthreads();
  const int adjb = b * CN * CN;
  int ibeg = 1 + 64 * half;
  int iend = half ? 128 : 65;
  for (int i = ibeg + grp; i < iend; i += 16) {
    float f1 = f1int[k * 128 + (i - 1)];
    int j1 = 1 + c, j2 = 65 + c;
    float w1 = 0.f, w2 = 0.f;
    if (adj[adjb + i * CN + j1]) w1 = fexpf(leakyf(f1 + f2s[j1 - 1]));
    if (j2 < 128 && adj[adjb + i * CN + j2]) w2 = fexpf(leakyf(f1 + f2s[j2 - 1]));
    wbuf[grp][c] = w1;
    wbuf[grp][64 + c] = w2;
    float rs = wredf(w1 + w2);
    float acc = 0.f;
    #pragma unroll 4
    for (int jj = 0; jj < 127; ++jj)
      acc += wbuf[grp][jj] * hs[jj * CGH + c];
    if (c == 0) wS[(b * 4 + k) * 128 + i] = rs;
    U[((b * 4 + k) * 128 + i) * CGH + c] = acc;
  }
}

// htok / f1tok / f2tok [r12 verbatim]
__global__ void k_htok(const float* __restrict__ lo, const float* __restrict__ Wh,
                       const float* __restrict__ ah, float* __restrict__ htok,
                       float* __restrict__ f1tok, float* __restrict__ f2tok) {
  __shared__ float ls[8][CH];
  int m0 = blockIdx.x * 8;
  int tid = threadIdx.x;
  int k = tid >> 6, c = tid & 63;
  for (int idx = tid; idx < 8 * CH; idx += 256) {
    int r = idx >> 8, d = idx & 255;
    ls[r][d] = lo[(m0 + r) * CH + d];
  }
  __syncthreads();
  float acc[8];
  #pragma unroll
  for (int r = 0; r < 8; ++r) acc[r] = 0.f;
  #pragma unroll 4
  for (int d = 0; d < CH; ++d) {
    float w = Wh[(k * CH + d) * CGH + c];
    #pragma unroll
    for (int r = 0; r < 8; ++r) acc[r] += w * ls[r][d];
  }
  float a1 = ah[k * 128 + c], a2 = ah[k * 128 + 64 + c];
  #pragma unroll
  for (int r = 0; r < 8; ++r) {
    htok[(m0 + r) * CH + tid] = acc[r];
    float r1 = wredf(acc[r] * a1);
    float r2 = wredf(acc[r] * a2);
    if (c == 0) { f1tok[(m0 + r) * CNH + k] = r1; f2tok[(m0 + r) * CNH + k] = r2; }
  }
}

// Per-token fused GAT layer-2 + logits; bitmask adjacency; fast exp. [r15 verbatim]
__global__ __launch_bounds__(256) void k_perm3(
    const float* __restrict__ lo, const float* __restrict__ htok,
    const float* __restrict__ f1tok, const float* __restrict__ f2tok,
    const float* __restrict__ hint, const float* __restrict__ f1int,
    const float* __restrict__ f2int, const float* __restrict__ U,
    const float* __restrict__ wS, const float* __restrict__ woao1,
    const float* __restrict__ woao2, const unsigned long long* __restrict__ masks,
    const float* __restrict__ Wo, const float* __restrict__ Wl,
    const float* __restrict__ bl, const int* __restrict__ seq_lens,
    float* __restrict__ out) {
  int m = blockIdx.x;
  int b = m >> 6, s = m & 63;
  int tid = threadIdx.x;
  int k = tid >> 6, c = tid & 63;

  __shared__ float ht[CH];
  __shared__ float s1[CNH][CN];
  __shared__ float s2[CNH][CN];
  __shared__ float w0[CNH][CN];
  __shared__ float x10[CH];
  __shared__ float f22[CN];
  __shared__ float w2s[CN];
  __shared__ float ybuf[CH];
  __shared__ float gbuf[CH];
  __shared__ float part[2][CV];
  __shared__ int   list[CN];
  __shared__ int   cnt;
  __shared__ float f12s, f220s, den2s;

  const unsigned long long c0lo = masks[b * 4 + 0], c0hi = masks[b * 4 + 1];
  const unsigned long long r0lo = masks[b * 4 + 2], r0hi = masks[b * 4 + 3];

  ht[tid] = htok[m * CH + tid];
  float f1t = f1tok[m * CNH + k];
  float f2t = f2tok[m * CNH + k];

  if (k == 0) {
    int j1 = 1 + c;
    int j2 = 65 + c;
    bool fl1 = bit128(r0lo, r0hi, j1);
    bool fl2 = (j2 < CN) && bit128(r0lo, r0hi, j2);
    unsigned long long b1 = __ballot(fl1);
    unsigned long long b2 = __ballot(fl2);
    unsigned long long below = (1ull << c) - 1ull;
    int n1 = __popcll(b1);
    if (fl1) list[__popcll(b1 & below)] = j1;
    if (fl2) list[n1 + __popcll(b2 & below)] = j2;
    if (c == 0) cnt = n1 + __popcll(b2);
  }

  for (int idx = tid; idx < CNH * CN; idx += 256) {
    int k2 = idx >> 7, i = idx & 127;
    if (i == 0) continue;
    float t0 = 0.f;
    if (bit128(c0lo, c0hi, i)) t0 = fexpf(leakyf(f1int[k2 * 128 + i - 1] + f2tok[m * CNH + k2]));
    float rd = 1.f / (wS[(b * 4 + k2) * 128 + i] + t0);
    s1[k2][i] = rd;
    s2[k2][i] = t0 * rd;
  }

  float den0;
  {
    int j1 = c, j2 = c + 64;
    float e1 = leakyf(f1t + (j1 == 0 ? f2t : f2int[k * 128 + j1 - 1]));
    float wj1 = bit128(r0lo, r0hi, j1) ? fexpf(e1) : 0.f;
    float e2 = leakyf(f1t + f2int[k * 128 + j2 - 1]);
    float wj2 = bit128(r0lo, r0hi, j2) ? fexpf(e2) : 0.f;
    w0[k][j1] = wj1;
    w0[k][j2] = wj2;
    den0 = wredf(wj1 + wj2);
  }
  __syncthreads();
  const int na = cnt;

  {
    float acc = w0[k][0] * ht[tid];
    #pragma unroll 4
    for (int l = 0; l < na; ++l) {
      int j = list[l];
      acc += w0[k][j] * hint[(k * 128 + j - 1) * CGH + c];
    }
    x10[tid] = eluf(acc / den0);
  }
  __syncthreads();

  if (k == 0) {
    float p = x10[c] * woao1[c] + x10[c + 64] * woao1[c + 64]
            + x10[c + 128] * woao1[c + 128] + x10[c + 192] * woao1[c + 192];
    p = wredf(p);
    if (c == 0) f12s = p;
  }
  if (k == 1) {
    float p = x10[c] * woao2[c] + x10[c + 64] * woao2[c + 64]
            + x10[c + 128] * woao2[c + 128] + x10[c + 192] * woao2[c + 192];
    p = wredf(p);
    if (c == 0) f220s = p;
  }
  for (int l = k; l < na; l += 4) {
    int j = list[l];
    float p = 0.f;
    #pragma unroll
    for (int kk = 0; kk < 4; ++kk) {
      float u = U[((b * 4 + kk) * 128 + j) * CGH + c];
      float val = eluf(u * s1[kk][j] + s2[kk][j] * ht[kk * 64 + c]);
      p += val * woao2[kk * 64 + c];
    }
    p = wredf(p);
    if (c == 0) f22[l] = p;
  }
  __syncthreads();

  float w20 = fexpf(leakyf(f12s + f220s));
  if (tid < na) w2s[tid] = fexpf(leakyf(f12s + f22[tid]));
  __syncthreads();
  if (k == 0) {
    float v = (c < na ? w2s[c] : 0.f) + (c + 64 < na ? w2s[c + 64] : 0.f);
    v = wredf(v);
    if (c == 0) den2s = v + w20;
  }

  {
    float yacc = w20 * x10[tid];
    #pragma unroll 4
    for (int l = 0; l < na; ++l) {
      int j = list[l];
      float u = U[((b * 4 + k) * 128 + j) * CGH + c];
      float val = eluf(u * s1[k][j] + s2[k][j] * ht[tid]);
      yacc += w2s[l] * val;
    }
    ybuf[tid] = yacc;
  }
  __syncthreads();

  float hacc = 0.f;
  #pragma unroll 8
  for (int kk = 0; kk < CH; ++kk) hacc += ybuf[kk] * Wo[kk * CH + tid];
  float g = eluf(hacc / den2s) + lo[m * CH + tid];
  gbuf[tid] = g;
  __syncthreads();

  {
    int col = tid & 127, hh = tid >> 7;
    float acc = 0.f;
    #pragma unroll 8
    for (int cc = hh * 128; cc < hh * 128 + 128; ++cc) acc += gbuf[cc] * Wl[cc * CV + col];
    part[hh][col] = acc;
  }
  __syncthreads();
  if (tid < CV) {
    float r = part[0][tid] + part[1][tid] + bl[tid];
    out[m * CV + tid] = (s < seq_lens[b]) ? r : 0.f;
  }
}

}  // namespace

extern "C" void kernel_launch(void* const* d_in, const int* in_sizes, int n_in,
                              void* d_out, int out_size, void* d_ws, size_t ws_size,
                              hipStream_t stream) {
  const float* hidden   = (const float*)d_in[0];
  const int*   seq_lens = (const int*)d_in[1];
  const int*   forced   = (const int*)d_in[2];
  const int*   adj      = (const int*)d_in[3];
  const float* intent   = (const float*)d_in[4];
  const float* emb      = (const float*)d_in[5];
  const float* initt    = (const float*)d_in[6];
  const float* W_ih     = (const float*)d_in[7];
  const float* W_hh     = (const float*)d_in[8];
  const float* b_ih     = (const float*)d_in[9];
  const float* b_hh     = (const float*)d_in[10];
  const float* Wh       = (const float*)d_in[11];
  const float* ah       = (const float*)d_in[12];
  const float* Wo       = (const float*)d_in[13];
  const float* ao       = (const float*)d_in[14];
  const float* Wl       = (const float*)d_in[15];
  const float* bl       = (const float*)d_in[16];
  float* out = (float*)d_out;

  // Layout (1 f16x2 = 1 float slot — verified r12).
  float* ws    = (float*)d_ws;
  float* WdF   = ws;                        // QLDS*CG = 36864 slots
  float* WsF   = WdF + QLDS * CG;           // QSTR*CG = 94208 slots
  float* xg    = WsF + QSTR * CG;           // 2097152
  float* lo    = xg + CM * CG;              // 524288
  float* htok  = lo + CM * CH;              // 524288
  float* f1tok = htok + CM * CH;            // 8192
  float* f2tok = f1tok + CM * CNH;          // 8192
  float* hint  = f2tok + CM * CNH;          // 32768
  float* f1int = hint + CNH * 128 * CGH;    // 512
  float* f2int = f1int + CNH * 128;         // 512
  float* U     = f2int + CNH * 128;         // 1048576
  float* wS    = U + CB * CNH * 128 * CGH;  // 16384
  float* woao1 = wS + CB * CNH * 128;       // 256
  float* woao2 = woao1 + CH;                // 256
  unsigned long long* masks = (unsigned long long*)(woao2 + CH);  // 32*4 u64
  f16x2* Wd    = (f16x2*)WdF;
  f16x2* Wsp   = (f16x2*)WsF;

  k_prep_xg<<<545, 256, 0, stream>>>(hidden, forced, emb, initt, W_ih, b_ih, b_hh, xg,
                                     W_hh, intent, Wh, ah, Wo, ao, adj,
                                     Wd, Wsp, hint, f1int, f2int, woao1, woao2, masks);
  k_lstm_u<<<CB + CB * CNH * 2, 1024, 0, stream>>>(xg, Wd, Wsp, lo,
                                                   hint, f1int, f2int, adj, U, wS);
  k_htok<<<CM / 8, 256, 0, stream>>>(lo, Wh, ah, htok, f1tok, f2tok);
  k_perm3<<<CM, 256, 0, stream>>>(lo, htok, f1tok, f2tok, hint, f1int, f2int,
                                  U, wS, woao1, woao2, masks, Wo, Wl, bl, seq_lens, out);
}

// Round 21
// 374.454 us; speedup vs baseline: 1.1166x; 1.0025x over previous
//
#include <hip/hip_runtime.h>
#include <hip/hip_bf16.h>

namespace {

constexpr int CB   = 32;            // batch
constexpr int CS   = 64;            // seq len
constexpr int CDIN = 256;           // encoder hidden
constexpr int CH   = 256;           // LSTM hidden / GAT feature
constexpr int CE   = 128;           // embedding dim
constexpr int CV   = 128;           // vocab
constexpr int CGH  = 64;            // per-head GAT dim
constexpr int CNH  = 4;             // heads
constexpr int CN   = 128;           // graph nodes
constexpr int CDX  = CDIN + CE;     // 384 LSTM input
constexpr int CG   = 4 * CH;        // 1024 gates
constexpr int CM   = CB * CS;       // 2048 tokens
constexpr int QLDS = 36;            // weight pairs per gate in LDS (144 KB)
constexpr int QSTR = 128 - QLDS;    // 92 streamed pairs (23 f16x8 chunks)
constexpr int NCH  = QSTR / 4;      // 23 streamed chunks

typedef _Float16 f16x2 __attribute__((ext_vector_type(2)));   // 4 B = 1 float slot
typedef _Float16 f16x8 __attribute__((ext_vector_type(8)));
typedef float    f32x4 __attribute__((ext_vector_type(4)));

__device__ __forceinline__ float leakyf(float x) { return x >= 0.f ? x : 0.2f * x; }
__device__ __forceinline__ float fexpf(float x)  { return __expf(x); }
__device__ __forceinline__ float eluf(float x)   { return x > 0.f ? x : __expf(x) - 1.f; }
__device__ __forceinline__ float sigmf(float x)  { return 1.f / (1.f + __expf(-x)); }
__device__ __forceinline__ float tanhfast(float x) { return 1.f - 2.f / (__expf(2.f * x) + 1.f); }
__device__ __forceinline__ float wredf(float v) {
  #pragma unroll
  for (int off = 32; off; off >>= 1) v += __shfl_xor(v, off);
  return v;
}
__device__ __forceinline__ bool bit128(unsigned long long lo, unsigned long long hi, int j) {
  return ((j < 64 ? (lo >> j) : (hi >> (j - 64))) & 1ull) != 0;
}
#define F2(a, b, c) __builtin_amdgcn_fdot2((a), (b), (c), false)
#define PAIR0(v) __builtin_shufflevector((v), (v), 0, 1)
#define PAIR1(v) __builtin_shufflevector((v), (v), 2, 3)
#define PAIR2(v) __builtin_shufflevector((v), (v), 4, 5)
#define PAIR3(v) __builtin_shufflevector((v), (v), 6, 7)

// Merged xg + prep kernel, 545 blocks x 256 threads. [r18 verbatim]
__global__ __launch_bounds__(256) void k_prep_xg(
    const float* __restrict__ hidden, const int* __restrict__ forced,
    const float* __restrict__ emb, const float* __restrict__ initt,
    const float* __restrict__ Wih, const float* __restrict__ bih,
    const float* __restrict__ bhh, float* __restrict__ xg,
    const float* __restrict__ Whh, const float* __restrict__ intent,
    const float* __restrict__ Wh, const float* __restrict__ ah,
    const float* __restrict__ Wo, const float* __restrict__ ao,
    const int* __restrict__ adj,
    f16x2* __restrict__ Wd, f16x2* __restrict__ Ws,
    float* __restrict__ hint, float* __restrict__ f1int, float* __restrict__ f2int,
    float* __restrict__ woao1, float* __restrict__ woao2,
    unsigned long long* __restrict__ masks) {
  __shared__ __align__(16) char pxs[12288];
  int tid = threadIdx.x;
  int bid = blockIdx.x;

  if (bid < 256) {                  // ---- xg path
    f32x4 (*xs)[CDX / 4] = (f32x4(*)[CDX / 4])pxs;
    int m0 = bid * 8;
    for (int idx = tid; idx < 8 * (CDX / 4); idx += 256) {
      int r = idx / (CDX / 4), q = idx - r * (CDX / 4);
      int m = m0 + r;
      f32x4 v;
      if (q < CDIN / 4) {
        v = ((const f32x4*)hidden)[m * (CDIN / 4) + q];
      } else {
        int e4 = q - CDIN / 4;
        if ((m & 63) == 0) v = ((const f32x4*)initt)[e4];
        else               v = ((const f32x4*)emb)[forced[m - 1] * (CE / 4) + e4];
      }
      xs[r][q] = v;
    }
    __syncthreads();
    int g0 = tid * 4;
    float acc[8][4];
    #pragma unroll
    for (int r = 0; r < 8; ++r)
      #pragma unroll
      for (int jj = 0; jj < 4; ++jj) acc[r][jj] = 0.f;
    const f32x4* w0 = (const f32x4*)(Wih + (g0 + 0) * CDX);
    const f32x4* w1 = (const f32x4*)(Wih + (g0 + 1) * CDX);
    const f32x4* w2 = (const f32x4*)(Wih + (g0 + 2) * CDX);
    const f32x4* w3 = (const f32x4*)(Wih + (g0 + 3) * CDX);
    #pragma unroll 2
    for (int q = 0; q < CDX / 4; ++q) {
      f32x4 wa = w0[q], wb = w1[q], wc = w2[q], wd4 = w3[q];
      #pragma unroll
      for (int r = 0; r < 8; ++r) {
        f32x4 xv = xs[r][q];
        acc[r][0] += wa.x * xv.x + wa.y * xv.y + wa.z * xv.z + wa.w * xv.w;
        acc[r][1] += wb.x * xv.x + wb.y * xv.y + wb.z * xv.z + wb.w * xv.w;
        acc[r][2] += wc.x * xv.x + wc.y * xv.y + wc.z * xv.z + wc.w * xv.w;
        acc[r][3] += wd4.x * xv.x + wd4.y * xv.y + wd4.z * xv.z + wd4.w * xv.w;
      }
    }
    f32x4 bias = { bih[g0] + bhh[g0], bih[g0 + 1] + bhh[g0 + 1],
                   bih[g0 + 2] + bhh[g0 + 2], bih[g0 + 3] + bhh[g0 + 3] };
    #pragma unroll
    for (int r = 0; r < 8; ++r) {
      f32x4 st = { acc[r][0] + bias.x, acc[r][1] + bias.y,
                   acc[r][2] + bias.z, acc[r][3] + bias.w };
      ((f32x4*)xg)[((m0 + r) * CG + g0) / 4] = st;
    }
    return;
  }

  int pb = bid - 256;
  if (pb < 256) {                   // ---- W_hh pack
    int g = pb * 4 + (tid >> 6);
    int c = tid & 63;
    const float2* row = (const float2*)(Whh + g * CH);
    #pragma unroll
    for (int hh = 0; hh < 2; ++hh) {
      int q = c + 64 * hh;
      float2 wp = row[q];
      f16x2 w = { (_Float16)wp.x, (_Float16)wp.y };
      if (q < QLDS) {
        Wd[q * CG + g] = w;
      } else {
        int qs = q - QLDS, jc = qs >> 2, sub = qs & 3;
        Ws[(jc * CG + g) * 4 + sub] = w;
      }
    }
  } else if (pb < 272) {            // ---- hint
    float (*ls)[CH] = (float(*)[CH])pxs;
    int i0 = (pb - 256) * 8;
    int k = tid >> 6, c = tid & 63;
    for (int idx = tid; idx < 8 * CH; idx += 256) {
      int r = idx >> 8, d = idx & 255;
      int i = i0 + r;
      ls[r][d] = (i < 127) ? intent[i * CH + d] : 0.f;
    }
    __syncthreads();
    float acc[8];
    #pragma unroll
    for (int r = 0; r < 8; ++r) acc[r] = 0.f;
    #pragma unroll 4
    for (int d = 0; d < CH; ++d) {
      float w = Wh[(k * CH + d) * CGH + c];
      #pragma unroll
      for (int r = 0; r < 8; ++r) acc[r] += w * ls[r][d];
    }
    float a1 = ah[k * 128 + c], a2 = ah[k * 128 + 64 + c];
    #pragma unroll
    for (int r = 0; r < 8; ++r) {
      int i = i0 + r;
      float r1 = wredf(acc[r] * a1);
      float r2 = wredf(acc[r] * a2);
      if (i < 127) {
        hint[(k * 128 + i) * CGH + c] = acc[r];
        if (c == 0) { f1int[k * 128 + i] = r1; f2int[k * 128 + i] = r2; }
      }
    }
  } else if (pb < 288) {            // ---- woao
    int wave = tid >> 6, c = tid & 63;
    #pragma unroll
    for (int it = 0; it < 8; ++it) {
      int o = (pb - 272) * 32 + it * 4 + wave;
      int orow = (o < 256) ? o : o - 256;
      int abase = (o < 256) ? 0 : CH;
      const float* row = Wo + orow * CH;
      float acc = row[c] * ao[abase + c] + row[64 + c] * ao[abase + 64 + c]
                + row[128 + c] * ao[abase + 128 + c] + row[192 + c] * ao[abase + 192 + c];
      acc = wredf(acc);
      if (c == 0) {
        if (o < 256) woao1[o] = acc;
        else         woao2[o - 256] = acc;
      }
    }
  } else {                          // ---- adjacency masks
    int wave = tid >> 6, c = tid & 63;
    for (int b = 0; b < CB; ++b) {
      const int base = b * CN * CN;
      int v;
      if (wave == 0)      v = adj[base + c * CN];
      else if (wave == 1) v = adj[base + (64 + c) * CN];
      else if (wave == 2) v = adj[base + c];
      else                v = adj[base + 64 + c];
      unsigned long long m = __ballot(v != 0);
      if (c == 0) masks[b * 4 + wave] = m;
    }
  }
}

// Merged LSTM + U kernel, 288 blocks x 1024 threads. [r20 structure]
// ONLY change vs r20: amdgpu_waves_per_eu(4,4) — LDS (152 KB) already caps
// occupancy at 1 block/CU = 4 waves/EU, so VGPRs up to 128 are free; the pin
// lets the allocator keep all 23 streamed f16x8 loads (92 VGPRs) in flight.
__global__ __launch_bounds__(1024) __attribute__((amdgpu_waves_per_eu(4, 4)))
void k_lstm_u(
    const float* __restrict__ xg, const f16x2* __restrict__ Wd,
    const f16x2* __restrict__ Ws, float* __restrict__ lo,
    const float* __restrict__ hint, const float* __restrict__ f1int,
    const float* __restrict__ f2int, const int* __restrict__ adj,
    float* __restrict__ U, float* __restrict__ wS) {
  __shared__ __align__(16) char smemraw[QLDS * CG * 4 + CG * 4 + (CH / 8) * 16];
  int tid = threadIdx.x;

  if (blockIdx.x < CB) {
    // ---------------- LSTM path ----------------
    f16x2* wd  = (f16x2*)smemraw;                         // 147456 B
    float* gbuf = (float*)(smemraw + QLDS * CG * 4);      // 4 KB
    f16x8* hs8  = (f16x8*)(smemraw + QLDS * CG * 4 + CG * 4);  // 512 B
    _Float16* hsh = (_Float16*)hs8;
    int b = blockIdx.x;
    int g = tid;

    for (int i = g; i < QLDS * CG; i += CG) wd[i] = Wd[i];
    if (g < CH) hsh[g] = (_Float16)0.f;
    float c = 0.f;
    __syncthreads();

    const float* xgb = xg + b * CS * CG;
    float nx = xgb[g];
    unsigned long long wsa = (unsigned long long)Ws;

    for (int t = 0; t < CS; ++t) {
      float acc0 = nx, acc1 = 0.f, acc2 = 0.f, acc3 = 0.f;
      if (t + 1 < CS) nx = xgb[(t + 1) * CG + g];
      asm volatile("" : "+v"(wsa));
      const f16x8* wsp = (const f16x8*)wsa;

      // Issue ALL 23 streamed loads first (92 VGPRs in flight).
      f16x8 wv[NCH];
      #pragma unroll
      for (int jc = 0; jc < NCH; ++jc) wv[jc] = wsp[jc * CG + g];

      // LDS-resident pairs 0..35 (chunks 0..8) — overlaps the load returns.
      #pragma unroll
      for (int hc = 0; hc < QLDS / 4; ++hc) {
        f16x8 hv = hs8[hc];
        acc0 = F2(wd[(4 * hc + 0) * CG + g], PAIR0(hv), acc0);
        acc1 = F2(wd[(4 * hc + 1) * CG + g], PAIR1(hv), acc1);
        acc2 = F2(wd[(4 * hc + 2) * CG + g], PAIR2(hv), acc2);
        acc3 = F2(wd[(4 * hc + 3) * CG + g], PAIR3(hv), acc3);
      }
      // Consume streamed chunks 9..31 in order (waitcnt descends).
      #pragma unroll
      for (int jc = 0; jc < NCH; ++jc) {
        f16x8 hv = hs8[QLDS / 4 + jc];
        acc0 = F2(PAIR0(wv[jc]), PAIR0(hv), acc0);
        acc1 = F2(PAIR1(wv[jc]), PAIR1(hv), acc1);
        acc2 = F2(PAIR2(wv[jc]), PAIR2(hv), acc2);
        acc3 = F2(PAIR3(wv[jc]), PAIR3(hv), acc3);
      }
      gbuf[g] = (acc0 + acc1) + (acc2 + acc3);
      __syncthreads();
      if (g < CH) {
        float gi = gbuf[g], gf = gbuf[CH + g], gg = gbuf[2 * CH + g], go = gbuf[3 * CH + g];
        c = sigmf(gf) * c + sigmf(gi) * tanhfast(gg);
        float h = sigmf(go) * tanhfast(c);
        lo[(b * CS + t) * CH + g] = h;
        hsh[g] = (_Float16)h;
      }
      __syncthreads();
    }
    return;
  }

  // ---------------- U path (r18 verbatim) ----------------
  float* hs = (float*)smemraw;
  float (*wbuf)[128] = (float(*)[128])(smemraw + 32512);
  float* f2s = (float*)(smemraw + 32512 + 8192);
  int ub = blockIdx.x - CB;
  int b = ub >> 3;
  int k = (ub >> 1) & 3;
  int half = ub & 1;
  int grp = tid >> 6, c = tid & 63;

  for (int idx = tid; idx < 127 * CGH; idx += 1024)
    hs[idx] = hint[k * 128 * CGH + idx];
  if (tid < 127) f2s[tid] = f2int[k * 128 + tid];
  __syncthreads();
  const int adjb = b * CN * CN;
  int ibeg = 1 + 64 * half;
  int iend = half ? 128 : 65;
  for (int i = ibeg + grp; i < iend; i += 16) {
    float f1 = f1int[k * 128 + (i - 1)];
    int j1 = 1 + c, j2 = 65 + c;
    float w1 = 0.f, w2 = 0.f;
    if (adj[adjb + i * CN + j1]) w1 = fexpf(leakyf(f1 + f2s[j1 - 1]));
    if (j2 < 128 && adj[adjb + i * CN + j2]) w2 = fexpf(leakyf(f1 + f2s[j2 - 1]));
    wbuf[grp][c] = w1;
    wbuf[grp][64 + c] = w2;
    float rs = wredf(w1 + w2);
    float acc = 0.f;
    #pragma unroll 4
    for (int jj = 0; jj < 127; ++jj)
      acc += wbuf[grp][jj] * hs[jj * CGH + c];
    if (c == 0) wS[(b * 4 + k) * 128 + i] = rs;
    U[((b * 4 + k) * 128 + i) * CGH + c] = acc;
  }
}

// htok / f1tok / f2tok [r12 verbatim]
__global__ void k_htok(const float* __restrict__ lo, const float* __restrict__ Wh,
                       const float* __restrict__ ah, float* __restrict__ htok,
                       float* __restrict__ f1tok, float* __restrict__ f2tok) {
  __shared__ float ls[8][CH];
  int m0 = blockIdx.x * 8;
  int tid = threadIdx.x;
  int k = tid >> 6, c = tid & 63;
  for (int idx = tid; idx < 8 * CH; idx += 256) {
    int r = idx >> 8, d = idx & 255;
    ls[r][d] = lo[(m0 + r) * CH + d];
  }
  __syncthreads();
  float acc[8];
  #pragma unroll
  for (int r = 0; r < 8; ++r) acc[r] = 0.f;
  #pragma unroll 4
  for (int d = 0; d < CH; ++d) {
    float w = Wh[(k * CH + d) * CGH + c];
    #pragma unroll
    for (int r = 0; r < 8; ++r) acc[r] += w * ls[r][d];
  }
  float a1 = ah[k * 128 + c], a2 = ah[k * 128 + 64 + c];
  #pragma unroll
  for (int r = 0; r < 8; ++r) {
    htok[(m0 + r) * CH + tid] = acc[r];
    float r1 = wredf(acc[r] * a1);
    float r2 = wredf(acc[r] * a2);
    if (c == 0) { f1tok[(m0 + r) * CNH + k] = r1; f2tok[(m0 + r) * CNH + k] = r2; }
  }
}

// Per-token fused GAT layer-2 + logits; bitmask adjacency; fast exp. [r15 verbatim]
__global__ __launch_bounds__(256) void k_perm3(
    const float* __restrict__ lo, const float* __restrict__ htok,
    const float* __restrict__ f1tok, const float* __restrict__ f2tok,
    const float* __restrict__ hint, const float* __restrict__ f1int,
    const float* __restrict__ f2int, const float* __restrict__ U,
    const float* __restrict__ wS, const float* __restrict__ woao1,
    const float* __restrict__ woao2, const unsigned long long* __restrict__ masks,
    const float* __restrict__ Wo, const float* __restrict__ Wl,
    const float* __restrict__ bl, const int* __restrict__ seq_lens,
    float* __restrict__ out) {
  int m = blockIdx.x;
  int b = m >> 6, s = m & 63;
  int tid = threadIdx.x;
  int k = tid >> 6, c = tid & 63;

  __shared__ float ht[CH];
  __shared__ float s1[CNH][CN];
  __shared__ float s2[CNH][CN];
  __shared__ float w0[CNH][CN];
  __shared__ float x10[CH];
  __shared__ float f22[CN];
  __shared__ float w2s[CN];
  __shared__ float ybuf[CH];
  __shared__ float gbuf[CH];
  __shared__ float part[2][CV];
  __shared__ int   list[CN];
  __shared__ int   cnt;
  __shared__ float f12s, f220s, den2s;

  const unsigned long long c0lo = masks[b * 4 + 0], c0hi = masks[b * 4 + 1];
  const unsigned long long r0lo = masks[b * 4 + 2], r0hi = masks[b * 4 + 3];

  ht[tid] = htok[m * CH + tid];
  float f1t = f1tok[m * CNH + k];
  float f2t = f2tok[m * CNH + k];

  if (k == 0) {
    int j1 = 1 + c;
    int j2 = 65 + c;
    bool fl1 = bit128(r0lo, r0hi, j1);
    bool fl2 = (j2 < CN) && bit128(r0lo, r0hi, j2);
    unsigned long long b1 = __ballot(fl1);
    unsigned long long b2 = __ballot(fl2);
    unsigned long long below = (1ull << c) - 1ull;
    int n1 = __popcll(b1);
    if (fl1) list[__popcll(b1 & below)] = j1;
    if (fl2) list[n1 + __popcll(b2 & below)] = j2;
    if (c == 0) cnt = n1 + __popcll(b2);
  }

  for (int idx = tid; idx < CNH * CN; idx += 256) {
    int k2 = idx >> 7, i = idx & 127;
    if (i == 0) continue;
    float t0 = 0.f;
    if (bit128(c0lo, c0hi, i)) t0 = fexpf(leakyf(f1int[k2 * 128 + i - 1] + f2tok[m * CNH + k2]));
    float rd = 1.f / (wS[(b * 4 + k2) * 128 + i] + t0);
    s1[k2][i] = rd;
    s2[k2][i] = t0 * rd;
  }

  float den0;
  {
    int j1 = c, j2 = c + 64;
    float e1 = leakyf(f1t + (j1 == 0 ? f2t : f2int[k * 128 + j1 - 1]));
    float wj1 = bit128(r0lo, r0hi, j1) ? fexpf(e1) : 0.f;
    float e2 = leakyf(f1t + f2int[k * 128 + j2 - 1]);
    float wj2 = bit128(r0lo, r0hi, j2) ? fexpf(e2) : 0.f;
    w0[k][j1] = wj1;
    w0[k][j2] = wj2;
    den0 = wredf(wj1 + wj2);
  }
  __syncthreads();
  const int na = cnt;

  {
    float acc = w0[k][0] * ht[tid];
    #pragma unroll 4
    for (int l = 0; l < na; ++l) {
      int j = list[l];
      acc += w0[k][j] * hint[(k * 128 + j - 1) * CGH + c];
    }
    x10[tid] = eluf(acc / den0);
  }
  __syncthreads();

  if (k == 0) {
    float p = x10[c] * woao1[c] + x10[c + 64] * woao1[c + 64]
            + x10[c + 128] * woao1[c + 128] + x10[c + 192] * woao1[c + 192];
    p = wredf(p);
    if (c == 0) f12s = p;
  }
  if (k == 1) {
    float p = x10[c] * woao2[c] + x10[c + 64] * woao2[c + 64]
            + x10[c + 128] * woao2[c + 128] + x10[c + 192] * woao2[c + 192];
    p = wredf(p);
    if (c == 0) f220s = p;
  }
  for (int l = k; l < na; l += 4) {
    int j = list[l];
    float p = 0.f;
    #pragma unroll
    for (int kk = 0; kk < 4; ++kk) {
      float u = U[((b * 4 + kk) * 128 + j) * CGH + c];
      float val = eluf(u * s1[kk][j] + s2[kk][j] * ht[kk * 64 + c]);
      p += val * woao2[kk * 64 + c];
    }
    p = wredf(p);
    if (c == 0) f22[l] = p;
  }
  __syncthreads();

  float w20 = fexpf(leakyf(f12s + f220s));
  if (tid < na) w2s[tid] = fexpf(leakyf(f12s + f22[tid]));
  __syncthreads();
  if (k == 0) {
    float v = (c < na ? w2s[c] : 0.f) + (c + 64 < na ? w2s[c + 64] : 0.f);
    v = wredf(v);
    if (c == 0) den2s = v + w20;
  }

  {
    float yacc = w20 * x10[tid];
    #pragma unroll 4
    for (int l = 0; l < na; ++l) {
      int j = list[l];
      float u = U[((b * 4 + k) * 128 + j) * CGH + c];
      float val = eluf(u * s1[k][j] + s2[k][j] * ht[tid]);
      yacc += w2s[l] * val;
    }
    ybuf[tid] = yacc;
  }
  __syncthreads();

  float hacc = 0.f;
  #pragma unroll 8
  for (int kk = 0; kk < CH; ++kk) hacc += ybuf[kk] * Wo[kk * CH + tid];
  float g = eluf(hacc / den2s) + lo[m * CH + tid];
  gbuf[tid] = g;
  __syncthreads();

  {
    int col = tid & 127, hh = tid >> 7;
    float acc = 0.f;
    #pragma unroll 8
    for (int cc = hh * 128; cc < hh * 128 + 128; ++cc) acc += gbuf[cc] * Wl[cc * CV + col];
    part[hh][col] = acc;
  }
  __syncthreads();
  if (tid < CV) {
    float r = part[0][tid] + part[1][tid] + bl[tid];
    out[m * CV + tid] = (s < seq_lens[b]) ? r : 0.f;
  }
}

}  // namespace

extern "C" void kernel_launch(void* const* d_in, const int* in_sizes, int n_in,
                              void* d_out, int out_size, void* d_ws, size_t ws_size,
                              hipStream_t stream) {
  const float* hidden   = (const float*)d_in[0];
  const int*   seq_lens = (const int*)d_in[1];
  const int*   forced   = (const int*)d_in[2];
  const int*   adj      = (const int*)d_in[3];
  const float* intent   = (const float*)d_in[4];
  const float* emb      = (const float*)d_in[5];
  const float* initt    = (const float*)d_in[6];
  const float* W_ih     = (const float*)d_in[7];
  const float* W_hh     = (const float*)d_in[8];
  const float* b_ih     = (const float*)d_in[9];
  const float* b_hh     = (const float*)d_in[10];
  const float* Wh       = (const float*)d_in[11];
  const float* ah       = (const float*)d_in[12];
  const float* Wo       = (const float*)d_in[13];
  const float* ao       = (const float*)d_in[14];
  const float* Wl       = (const float*)d_in[15];
  const float* bl       = (const float*)d_in[16];
  float* out = (float*)d_out;

  // Layout (1 f16x2 = 1 float slot — verified r12).
  float* ws    = (float*)d_ws;
  float* WdF   = ws;                        // QLDS*CG = 36864 slots
  float* WsF   = WdF + QLDS * CG;           // QSTR*CG = 94208 slots
  float* xg    = WsF + QSTR * CG;           // 2097152
  float* lo    = xg + CM * CG;              // 524288
  float* htok  = lo + CM * CH;              // 524288
  float* f1tok = htok + CM * CH;            // 8192
  float* f2tok = f1tok + CM * CNH;          // 8192
  float* hint  = f2tok + CM * CNH;          // 32768
  float* f1int = hint + CNH * 128 * CGH;    // 512
  float* f2int = f1int + CNH * 128;         // 512
  float* U     = f2int + CNH * 128;         // 1048576
  float* wS    = U + CB * CNH * 128 * CGH;  // 16384
  float* woao1 = wS + CB * CNH * 128;       // 256
  float* woao2 = woao1 + CH;                // 256
  unsigned long long* masks = (unsigned long long*)(woao2 + CH);  // 32*4 u64
  f16x2* Wd    = (f16x2*)WdF;
  f16x2* Wsp   = (f16x2*)WsF;

  k_prep_xg<<<545, 256, 0, stream>>>(hidden, forced, emb, initt, W_ih, b_ih, b_hh, xg,
                                     W_hh, intent, Wh, ah, Wo, ao, adj,
                                     Wd, Wsp, hint, f1int, f2int, woao1, woao2, masks);
  k_lstm_u<<<CB + CB * CNH * 2, 1024, 0, stream>>>(xg, Wd, Wsp, lo,
                                                   hint, f1int, f2int, adj, U, wS);
  k_htok<<<CM / 8, 256, 0, stream>>>(lo, Wh, ah, htok, f1tok, f2tok);
  k_perm3<<<CM, 256, 0, stream>>>(lo, htok, f1tok, f2tok, hint, f1int, f2int,
                                  U, wS, woao1, woao2, masks, Wo, Wl, bl, seq_lens, out);
}